// Round 4
// baseline (1013.665 us; speedup 1.0000x reference)
//
#include <hip/hip_runtime.h>
#include <cstdint>
#include <cstddef>

#define T_TOK 8192
#define E_NUM 8
#define D_DIM 1024
#define H_DIM 4096
#define MAXTILES 72
#define TILE 256

typedef __attribute__((ext_vector_type(8))) short short8;
typedef __attribute__((ext_vector_type(4))) float f32x4;
typedef __attribute__((ext_vector_type(8))) unsigned short ushort8v;
typedef __attribute__((ext_vector_type(4))) unsigned short ushort4v;

__device__ __forceinline__ unsigned short f2b(float f) {
  unsigned int u = __float_as_uint(f);
  u += 0x7fffu + ((u >> 16) & 1u);   // round-to-nearest-even
  return (unsigned short)(u >> 16);
}

__device__ __forceinline__ void async16(const void* g, void* l) {
  __builtin_amdgcn_global_load_lds((const __attribute__((address_space(1))) void*)g,
                                   (__attribute__((address_space(3))) void*)l, 16, 0, 0);
}

// ---------------- router: noisy top-2 + sparse softmax gates ----------------
__global__ void router_kernel(const float* __restrict__ logits, const float* __restrict__ noise,
                              int* __restrict__ counts, int* __restrict__ ti, float* __restrict__ tg) {
  int tk = blockIdx.x * blockDim.x + threadIdx.x;
  if (tk >= T_TOK) return;
  float nz[E_NUM];
#pragma unroll
  for (int e = 0; e < E_NUM; ++e) {
    float l = logits[tk * E_NUM + e];
    float sp = fmaxf(l, 0.f) + log1pf(expf(-fabsf(l)));  // stable softplus
    nz[e] = l + noise[tk * E_NUM + e] * sp;
  }
  int i1 = 0; float v1 = nz[0];
#pragma unroll
  for (int e = 1; e < E_NUM; ++e) if (nz[e] > v1) { v1 = nz[e]; i1 = e; }
  int i2 = -1; float v2 = -3.0e38f;
#pragma unroll
  for (int e = 0; e < E_NUM; ++e) if (e != i1 && nz[e] > v2) { v2 = nz[e]; i2 = e; }
  float ex = expf(v2 - v1);           // <= 1
  float g1 = 1.f / (1.f + ex);
  float g2 = ex / (1.f + ex);
  int s1 = atomicAdd(&counts[i1], 1);
  int s2 = atomicAdd(&counts[i2], 1);
  ti[tk*4+0] = i1; ti[tk*4+1] = s1; ti[tk*4+2] = i2; ti[tk*4+3] = s2;
  tg[tk*2+0] = g1; tg[tk*2+1] = g2;
}

// ---------------- offsets + M-tile table (256-row tiles) ----------------
__global__ void setup_kernel(const int* __restrict__ counts, int* __restrict__ offs,
                             int* __restrict__ tab) {
  int o = 0;
  for (int e = 0; e < E_NUM; ++e) { offs[e] = o; o += counts[e]; }
  offs[E_NUM] = o;
  int mt = 0;
  for (int e = 0; e < E_NUM; ++e)
    for (int m0 = 0; m0 < counts[e]; m0 += TILE) { tab[mt*2] = e; tab[mt*2+1] = m0; ++mt; }
  for (; mt < MAXTILES; ++mt) { tab[mt*2] = -1; tab[mt*2+1] = 0; }
}

// ---------------- gather x rows into expert-sorted bf16 ----------------
__global__ void gather_kernel(const float* __restrict__ x, const int* __restrict__ ti,
                              const float* __restrict__ tg, const int* __restrict__ offs,
                              unsigned short* __restrict__ xg, int* __restrict__ stok,
                              float* __restrict__ sg) {
  const int tk = blockIdx.x, t = threadIdx.x;
  const int i1 = ti[tk*4+0], s1 = ti[tk*4+1], i2 = ti[tk*4+2], s2 = ti[tk*4+3];
  const int r1 = offs[i1] + s1, r2 = offs[i2] + s2;
  if (t == 0) {
    stok[r1] = tk; sg[r1] = tg[tk*2+0];
    stok[r2] = tk; sg[r2] = tg[tk*2+1];
  }
  const float4 v = *(const float4*)(x + (size_t)tk * D_DIM + t * 4);
  ushort4v bb; bb.x = f2b(v.x); bb.y = f2b(v.y); bb.z = f2b(v.z); bb.w = f2b(v.w);
  *(ushort4v*)(xg + (size_t)r1 * D_DIM + t * 4) = bb;
  *(ushort4v*)(xg + (size_t)r2 * D_DIM + t * 4) = bb;
}

// ---------------- fp32 [K][N] -> bf16 [N][K] transpose (per expert slice) ----------------
__global__ void transpose_kernel(const float* __restrict__ W, unsigned short* __restrict__ Wt,
                                 int K, int N) {
  const int e = blockIdx.z;
  const float* We = W + (size_t)e * K * N;
  unsigned short* Wte = Wt + (size_t)e * K * N;
  __shared__ __align__(16) unsigned short tb[64 * 72];   // [n][k], pad 72 (144B row, 16B-aligned)
  const int n0 = blockIdx.x * 64, k0 = blockIdx.y * 64;
  const int t = threadIdx.x;
  const int kr = t >> 4;            // 0..15
  const int c4 = (t & 15) * 4;      // 0..60
#pragma unroll
  for (int rr = 0; rr < 4; ++rr) {
    int k = kr + rr * 16;
    const float4 v = *(const float4*)(We + (size_t)(k0 + k) * N + n0 + c4);
    tb[(c4+0)*72 + k] = f2b(v.x);
    tb[(c4+1)*72 + k] = f2b(v.y);
    tb[(c4+2)*72 + k] = f2b(v.z);
    tb[(c4+3)*72 + k] = f2b(v.w);
  }
  __syncthreads();
  const int n = t >> 2, kq = (t & 3) * 16;
  ushort8v a = *(const ushort8v*)&tb[n*72 + kq];
  ushort8v b = *(const ushort8v*)&tb[n*72 + kq + 8];
  *(ushort8v*)(Wte + (size_t)(n0+n)*K + k0 + kq) = a;
  *(ushort8v*)(Wte + (size_t)(n0+n)*K + k0 + kq + 8) = b;
}

// ---------------- grouped GEMM, B^T bf16, 256x256 tile, 8 waves, 2-PHASE ----------------
// The guide's verified MINIMUM 2-phase template (T3 recipe box; m230 V0 = 682 TF,
// m248 2ph = 655-666 TF at exactly this grouped K=1024/256^2 shape), replacing the
// R3 8-phase port that nulled (MfmaUtil 17% — naive 8ph port, m232 outcome).
//
// Per K-tile (BK=64): ONE barrier, ONE vmcnt(0):
//   STAGE(buf^1, kt+1)   // 8 global_load_lds issued FIRST
//   ds_read 24 x b128 from buf[cur]   // compiler inserts counted lgkmcnt
//   setprio(1); 64 x MFMA; setprio(0)
//   vmcnt(0)             // stage issued ~full K-tile ago -> mostly landed
//   s_barrier
// Hazards: reads target buf[cur], stage writes buf[cur^1] (disjoint); all reads
// of buf[cur] complete before their consuming MFMA (compiler lgkm waits), hence
// before the barrier; next iter's overwrite of buf[cur] is issued after it.
//
// Geometry: 512 threads = 8 waves (2M x 4N), wave output 128x64 = acc[8][4].
// LDS: 2 buffers x (A[256][64] | B[256][64]) bf16 = 128 KiB (1 block/CU).
//
// Bank-conflict swizzle (verified ZERO conflicts + correct in R3, kept verbatim):
// rows are 128B = 8 chunks of 16B. Physical chunk c of row r holds GLOBAL chunk
// c ^ (r&7). Staging thread (per 128-row region): row r = wv*8 + (lane>>3) (+64),
// phys chunk lane&7 -> loads global chunk (lane&7)^(lane>>3). Reads fetch logical
// chunk (kk*4+fq) at phys ((kk*4+fq)^(fr&7)) -> 2-way max (free, m136).
//
// GEMM2: KSPLIT=1 (R2->R3 showed fewer splits strictly better: atomic RMW traffic
// halves to 64 MiB; real grid ~270 blocks ~= one full round at 1 block/CU).
//
// EPI 0: Hout[seg+m][N] = bf16(relu(acc + bias))
// EPI 1: atomicAdd(Out[tok[m]][n], (acc + bias) * gate[m])
template<int EPI, int NX, int KSPLIT>
__global__ __launch_bounds__(512, 2)
void gemm2p(const unsigned short* __restrict__ A, const unsigned short* __restrict__ Bt,
            const int K, const int N,
            const int* __restrict__ counts, const int* __restrict__ offs,
            const int* __restrict__ tab,
            const float* __restrict__ bias,
            unsigned short* __restrict__ Hout,
            float* __restrict__ Out,
            const int* __restrict__ slot_tok, const float* __restrict__ slot_gate) {
  constexpr int GRID = NX * MAXTILES * KSPLIT;   // 1152 (GEMM1) / 288 (GEMM2), %8==0
  constexpr int Q = GRID / 8;
  const int bid = blockIdx.x;
  // XCD-bijective chunked map; mt varies fastest within an XCD chunk so the
  // concurrent blocks of one XCD share a B-panel (L2-resident).
  const int lin = (bid & 7) * Q + (bid >> 3);
  const int mt  = lin % MAXTILES;
  const int u   = lin / MAXTILES;
  const int kb  = u % KSPLIT;
  const int xi  = u / KSPLIT;

  const int e = tab[mt*2];
  if (e < 0) return;
  const int m0  = tab[mt*2+1];
  const int cnt = counts[e];
  const int seg = offs[e];
  const int n0  = xi * TILE;
  const int KC  = K / KSPLIT;
  const int NT  = KC / 64;          // K-tiles in this block's slice
  const int ks  = kb * KC;          // k origin (shorts)

  // buf[2] x 64 KiB; per-buf byte layout: A0 @0, A1 @16384, B0 @32768, B1 @49152
  __shared__ __align__(16) short smem[2 * 32768];   // 128 KiB
  __shared__ int   s_tok[TILE];
  __shared__ float s_g[TILE];

  const int t = threadIdx.x;
  const int lane = t & 63;
  const int wv = t >> 6;
  const int wm = wv >> 2, wn = wv & 3;        // 2 x 4 wave grid
  const int fr = lane & 15, fq = lane >> 4;

  if (EPI == 1 && t < TILE) {
    int rl = m0 + t;
    if (rl < cnt) { s_tok[t] = slot_tok[seg + rl]; s_g[t] = slot_gate[seg + rl]; }
    else          { s_tok[t] = 0;                  s_g[t] = 0.f; }
  }
  __syncthreads();   // real barrier (with drain) BEFORE prologue issues

  const unsigned short* Ae = A + (size_t)seg * K;
  const unsigned short* Be = Bt + (size_t)e * N * K + (size_t)n0 * K;

  // ---- staging addresses: per 128-row region, thread covers rows rl and rl+64,
  // phys chunk lane&7 -> global chunk (lane&7)^(lane>>3), 16B each.
  const int rl   = wv * 8 + (lane >> 3);                  // 0..63
  const int swSt = ((lane & 7) ^ (lane >> 3)) * 8;        // shorts
  int am0 = m0 + rl;        am0 = am0 < cnt ? am0 : cnt - 1;
  int am1 = m0 + rl + 64;   am1 = am1 < cnt ? am1 : cnt - 1;
  int am2 = m0 + rl + 128;  am2 = am2 < cnt ? am2 : cnt - 1;
  int am3 = m0 + rl + 192;  am3 = am3 < cnt ? am3 : cnt - 1;
  const unsigned short* pa0 = Ae + (size_t)am0 * K + swSt;
  const unsigned short* pa1 = Ae + (size_t)am1 * K + swSt;
  const unsigned short* pa2 = Ae + (size_t)am2 * K + swSt;
  const unsigned short* pa3 = Ae + (size_t)am3 * K + swSt;
  const unsigned short* pb0 = Be + (size_t)(rl)       * K + swSt;
  const unsigned short* pb1 = Be + (size_t)(rl + 64)  * K + swSt;
  const unsigned short* pb2 = Be + (size_t)(rl + 128) * K + swSt;
  const unsigned short* pb3 = Be + (size_t)(rl + 192) * K + swSt;
  const int wvOff = wv * 1024;   // wave-uniform LDS dest (HW appends lane*16)

  auto stage = [&](int par, int ko) {    // all 4 regions: 8 global_load_lds
    char* d = (char*)smem + par * 65536 + wvOff;
    async16(pa0 + ko, d);          async16(pa1 + ko, d + 8192);
    async16(pa2 + ko, d + 16384);  async16(pa3 + ko, d + 24576);
    async16(pb0 + ko, d + 32768);  async16(pb1 + ko, d + 40960);
    async16(pb2 + ko, d + 49152);  async16(pb3 + ko, d + 57344);
  };

  // ---- read-side swizzled chunk offsets (shorts), lane-constant
  const int sw0 = ((0 * 4 + fq) ^ (fr & 7)) * 8;   // kk=0
  const int sw1 = ((1 * 4 + fq) ^ (fr & 7)) * 8;   // kk=1
  const int bl  = (wn & 1) * 64;                   // B local row base

  f32x4 acc[8][4];
#pragma unroll
  for (int i = 0; i < 8; ++i)
#pragma unroll
    for (int j = 0; j < 4; ++j) acc[i][j] = (f32x4){0.f, 0.f, 0.f, 0.f};

  // ---- prologue: stage K-tile 0 into buf0, drain, sync
  stage(0, ks);
  asm volatile("s_waitcnt vmcnt(0)" ::: "memory");
  asm volatile("s_barrier" ::: "memory");

  short8 aLo[4][2], aHi[4][2], b01[2][2], b23[2][2];

  for (int kt = 0; kt < NT; ++kt) {
    const int cur = kt & 1;
    // ---- phase A: issue next K-tile's stage FIRST (hides under reads+MFMA)
    if (kt + 1 < NT) stage(cur ^ 1, ks + (kt + 1) * 64);

    // ---- ds_read all 24 fragments of current K-tile
    const short* bR = smem + cur * 32768;
    const short* Aw = bR + wm * 8192;                 // this wave's A half (128 rows)
    const short* Bw = bR + 16384 + (wn >> 1) * 8192;  // this wave's B region
#pragma unroll
    for (int i = 0; i < 4; ++i) {
      int ro = (i * 16 + fr) * 64;
      aLo[i][0] = *(const short8*)&Aw[ro + sw0];
      aLo[i][1] = *(const short8*)&Aw[ro + sw1];
    }
#pragma unroll
    for (int i = 0; i < 4; ++i) {
      int ro = ((i + 4) * 16 + fr) * 64;
      aHi[i][0] = *(const short8*)&Aw[ro + sw0];
      aHi[i][1] = *(const short8*)&Aw[ro + sw1];
    }
#pragma unroll
    for (int j = 0; j < 2; ++j) {
      int ro = (bl + j * 16 + fr) * 64;
      b01[j][0] = *(const short8*)&Bw[ro + sw0];
      b01[j][1] = *(const short8*)&Bw[ro + sw1];
    }
#pragma unroll
    for (int j = 0; j < 2; ++j) {
      int ro = (bl + 32 + j * 16 + fr) * 64;
      b23[j][0] = *(const short8*)&Bw[ro + sw0];
      b23[j][1] = *(const short8*)&Bw[ro + sw1];
    }

    // ---- phase B: 64 MFMA (compiler inserts counted lgkmcnt before uses)
    __builtin_amdgcn_s_setprio(1);
#pragma unroll
    for (int i = 0; i < 4; ++i)
#pragma unroll
      for (int j = 0; j < 2; ++j) {
        acc[i][j]     = __builtin_amdgcn_mfma_f32_16x16x32_bf16(aLo[i][0], b01[j][0], acc[i][j], 0, 0, 0);
        acc[i][j]     = __builtin_amdgcn_mfma_f32_16x16x32_bf16(aLo[i][1], b01[j][1], acc[i][j], 0, 0, 0);
        acc[i][j+2]   = __builtin_amdgcn_mfma_f32_16x16x32_bf16(aLo[i][0], b23[j][0], acc[i][j+2], 0, 0, 0);
        acc[i][j+2]   = __builtin_amdgcn_mfma_f32_16x16x32_bf16(aLo[i][1], b23[j][1], acc[i][j+2], 0, 0, 0);
        acc[i+4][j]   = __builtin_amdgcn_mfma_f32_16x16x32_bf16(aHi[i][0], b01[j][0], acc[i+4][j], 0, 0, 0);
        acc[i+4][j]   = __builtin_amdgcn_mfma_f32_16x16x32_bf16(aHi[i][1], b01[j][1], acc[i+4][j], 0, 0, 0);
        acc[i+4][j+2] = __builtin_amdgcn_mfma_f32_16x16x32_bf16(aHi[i][0], b23[j][0], acc[i+4][j+2], 0, 0, 0);
        acc[i+4][j+2] = __builtin_amdgcn_mfma_f32_16x16x32_bf16(aHi[i][1], b23[j][1], acc[i+4][j+2], 0, 0, 0);
      }
    __builtin_amdgcn_s_setprio(0);

    // ---- single drain + single barrier per K-tile
    asm volatile("s_waitcnt vmcnt(0)" ::: "memory");
    asm volatile("s_barrier" ::: "memory");
  }

  if (EPI == 0) {
    const float* be = bias + (size_t)e * N;
#pragma unroll
    for (int j = 0; j < 4; ++j) {
      int col = n0 + wn*64 + j*16 + fr;
      float bv = be[col];
#pragma unroll
      for (int i = 0; i < 8; ++i) {
        int tl0 = wm*128 + i*16 + fq*4;      // tile-local row base
#pragma unroll
        for (int r = 0; r < 4; ++r) {
          int tlr = tl0 + r;
          if (m0 + tlr < cnt) {
            float v = acc[i][j][r] + bv;
            v = v > 0.f ? v : 0.f;
            Hout[(size_t)(seg + m0 + tlr) * N + col] = f2b(v);
          }
        }
      }
    }
  } else {
    const float* be = bias + (size_t)e * N;
#pragma unroll
    for (int j = 0; j < 4; ++j) {
      int col = n0 + wn*64 + j*16 + fr;
      float bv = (kb == 0) ? be[col] : 0.f;  // bias exactly once across k-splits
#pragma unroll
      for (int i = 0; i < 8; ++i) {
        int tl0 = wm*128 + i*16 + fq*4;
#pragma unroll
        for (int r = 0; r < 4; ++r) {
          int tlr = tl0 + r;
          if (m0 + tlr < cnt) {
            float v = (acc[i][j][r] + bv) * s_g[tlr];
            unsafeAtomicAdd(Out + (size_t)s_tok[tlr] * N + col, v);
          }
        }
      }
    }
  }
}

extern "C" void kernel_launch(void* const* d_in, const int* in_sizes, int n_in,
                              void* d_out, int out_size, void* d_ws, size_t ws_size,
                              hipStream_t stream) {
  const float* x      = (const float*)d_in[0];
  const float* logits = (const float*)d_in[1];
  const float* noise  = (const float*)d_in[2];
  const float* W1     = (const float*)d_in[3];
  const float* b1     = (const float*)d_in[4];
  const float* W2     = (const float*)d_in[5];
  const float* b2     = (const float*)d_in[6];
  float* out = (float*)d_out;

  char* ws = (char*)d_ws;
  size_t off = 0;
  auto alloc = [&](size_t b) { size_t o = off; off = (off + b + 255) & ~(size_t)255; return o; };
  size_t o_counts = alloc(E_NUM * 4);
  size_t o_offs   = alloc((E_NUM + 1) * 4);
  size_t o_tab    = alloc((size_t)MAXTILES * 2 * 4);
  size_t o_ti     = alloc((size_t)T_TOK * 4 * 4);
  size_t o_tg     = alloc((size_t)T_TOK * 2 * 4);
  size_t o_stok   = alloc((size_t)2 * T_TOK * 4);
  size_t o_sg     = alloc((size_t)2 * T_TOK * 4);
  size_t o_xg     = alloc((size_t)2 * T_TOK * D_DIM * 2);
  size_t o_w1t    = alloc((size_t)E_NUM * D_DIM * H_DIM * 2);
  size_t o_w2t    = alloc((size_t)E_NUM * D_DIM * H_DIM * 2);
  size_t o_h      = alloc((size_t)2 * T_TOK * H_DIM * 2);
  if (off > ws_size) return;   // ws tier too small — will show as clean validation failure

  int*            counts = (int*)(ws + o_counts);
  int*            offsp  = (int*)(ws + o_offs);
  int*            tab    = (int*)(ws + o_tab);
  int*            ti     = (int*)(ws + o_ti);
  float*          tg     = (float*)(ws + o_tg);
  int*            stok   = (int*)(ws + o_stok);
  float*          sg     = (float*)(ws + o_sg);
  unsigned short* xg     = (unsigned short*)(ws + o_xg);
  unsigned short* w1t    = (unsigned short*)(ws + o_w1t);
  unsigned short* w2t    = (unsigned short*)(ws + o_w2t);
  unsigned short* h      = (unsigned short*)(ws + o_h);

  hipMemsetAsync(out, 0, (size_t)out_size * sizeof(float), stream);
  hipMemsetAsync(counts, 0, E_NUM * sizeof(int), stream);

  router_kernel<<<T_TOK / 256, 256, 0, stream>>>(logits, noise, counts, ti, tg);
  setup_kernel<<<1, 1, 0, stream>>>(counts, offsp, tab);
  gather_kernel<<<T_TOK, 256, 0, stream>>>(x, ti, tg, offsp, xg, stok, sg);

  transpose_kernel<<<dim3(H_DIM/64, D_DIM/64, E_NUM), 256, 0, stream>>>(W1, w1t, D_DIM, H_DIM);
  transpose_kernel<<<dim3(D_DIM/64, H_DIM/64, E_NUM), 256, 0, stream>>>(W2, w2t, H_DIM, D_DIM);

  // GEMM1: 16 n-tiles, K=1024 (16 K-tiles). grid 1152.
  gemm2p<0, H_DIM/TILE, 1><<<dim3((H_DIM/TILE) * MAXTILES * 1), 512, 0, stream>>>(
      xg, w1t, D_DIM, H_DIM, counts, offsp, tab, b1, h, nullptr, nullptr, nullptr);
  // GEMM2: 4 n-tiles, no K-split (K=4096 -> 64 K-tiles). grid 288 (~1 round/CU).
  gemm2p<1, D_DIM/TILE, 1><<<dim3((D_DIM/TILE) * MAXTILES * 1), 512, 0, stream>>>(
      h, w2t, H_DIM, D_DIM, counts, offsp, tab, b2, nullptr, out, stok, sg);
}

// Round 5
// 942.616 us; speedup vs baseline: 1.0754x; 1.0754x over previous
//
#include <hip/hip_runtime.h>
#include <cstdint>
#include <cstddef>

#define T_TOK 8192
#define E_NUM 8
#define D_DIM 1024
#define H_DIM 4096
#define MAXTILES 136
#define TILE 128
#define BK 32
#define STAGES 2

typedef __attribute__((ext_vector_type(8))) short short8;
typedef __attribute__((ext_vector_type(4))) float f32x4;
typedef __attribute__((ext_vector_type(8))) unsigned short ushort8v;
typedef __attribute__((ext_vector_type(4))) unsigned short ushort4v;

__device__ __forceinline__ unsigned short f2b(float f) {
  unsigned int u = __float_as_uint(f);
  u += 0x7fffu + ((u >> 16) & 1u);   // round-to-nearest-even
  return (unsigned short)(u >> 16);
}

__device__ __forceinline__ void async16(const void* g, void* l) {
  __builtin_amdgcn_global_load_lds((const __attribute__((address_space(1))) void*)g,
                                   (__attribute__((address_space(3))) void*)l, 16, 0, 0);
}

// ---------------- router: noisy top-2 + sparse softmax gates ----------------
__global__ void router_kernel(const float* __restrict__ logits, const float* __restrict__ noise,
                              int* __restrict__ counts, int* __restrict__ ti, float* __restrict__ tg) {
  int tk = blockIdx.x * blockDim.x + threadIdx.x;
  if (tk >= T_TOK) return;
  float nz[E_NUM];
#pragma unroll
  for (int e = 0; e < E_NUM; ++e) {
    float l = logits[tk * E_NUM + e];
    float sp = fmaxf(l, 0.f) + log1pf(expf(-fabsf(l)));  // stable softplus
    nz[e] = l + noise[tk * E_NUM + e] * sp;
  }
  int i1 = 0; float v1 = nz[0];
#pragma unroll
  for (int e = 1; e < E_NUM; ++e) if (nz[e] > v1) { v1 = nz[e]; i1 = e; }
  int i2 = -1; float v2 = -3.0e38f;
#pragma unroll
  for (int e = 0; e < E_NUM; ++e) if (e != i1 && nz[e] > v2) { v2 = nz[e]; i2 = e; }
  float ex = expf(v2 - v1);           // <= 1
  float g1 = 1.f / (1.f + ex);
  float g2 = ex / (1.f + ex);
  int s1 = atomicAdd(&counts[i1], 1);
  int s2 = atomicAdd(&counts[i2], 1);
  ti[tk*4+0] = i1; ti[tk*4+1] = s1; ti[tk*4+2] = i2; ti[tk*4+3] = s2;
  tg[tk*2+0] = g1; tg[tk*2+1] = g2;
}

// ---------------- offsets + M-tile table ----------------
__global__ void setup_kernel(const int* __restrict__ counts, int* __restrict__ offs,
                             int* __restrict__ tab) {
  int o = 0;
  for (int e = 0; e < E_NUM; ++e) { offs[e] = o; o += counts[e]; }
  offs[E_NUM] = o;
  int mt = 0;
  for (int e = 0; e < E_NUM; ++e)
    for (int m0 = 0; m0 < counts[e]; m0 += TILE) { tab[mt*2] = e; tab[mt*2+1] = m0; ++mt; }
  for (; mt < MAXTILES; ++mt) { tab[mt*2] = -1; tab[mt*2+1] = 0; }
}

// ---------------- gather x rows into expert-sorted bf16 ----------------
__global__ void gather_kernel(const float* __restrict__ x, const int* __restrict__ ti,
                              const float* __restrict__ tg, const int* __restrict__ offs,
                              unsigned short* __restrict__ xg, int* __restrict__ stok,
                              float* __restrict__ sg) {
  const int tk = blockIdx.x, t = threadIdx.x;
  const int i1 = ti[tk*4+0], s1 = ti[tk*4+1], i2 = ti[tk*4+2], s2 = ti[tk*4+3];
  const int r1 = offs[i1] + s1, r2 = offs[i2] + s2;
  if (t == 0) {
    stok[r1] = tk; sg[r1] = tg[tk*2+0];
    stok[r2] = tk; sg[r2] = tg[tk*2+1];
  }
  const float4 v = *(const float4*)(x + (size_t)tk * D_DIM + t * 4);
  ushort4v bb; bb.x = f2b(v.x); bb.y = f2b(v.y); bb.z = f2b(v.z); bb.w = f2b(v.w);
  *(ushort4v*)(xg + (size_t)r1 * D_DIM + t * 4) = bb;
  *(ushort4v*)(xg + (size_t)r2 * D_DIM + t * 4) = bb;
}

// ---------------- fp32 [K][N] -> bf16 [N][K] transpose (per expert slice) ----------------
__global__ void transpose_kernel(const float* __restrict__ W, unsigned short* __restrict__ Wt,
                                 int K, int N) {
  const int e = blockIdx.z;
  const float* We = W + (size_t)e * K * N;
  unsigned short* Wte = Wt + (size_t)e * K * N;
  __shared__ __align__(16) unsigned short tb[64 * 72];   // [n][k], pad 72 (144B row, 16B-aligned)
  const int n0 = blockIdx.x * 64, k0 = blockIdx.y * 64;
  const int t = threadIdx.x;
  const int kr = t >> 4;            // 0..15
  const int c4 = (t & 15) * 4;      // 0..60
#pragma unroll
  for (int rr = 0; rr < 4; ++rr) {
    int k = kr + rr * 16;
    const float4 v = *(const float4*)(We + (size_t)(k0 + k) * N + n0 + c4);
    tb[(c4+0)*72 + k] = f2b(v.x);
    tb[(c4+1)*72 + k] = f2b(v.y);
    tb[(c4+2)*72 + k] = f2b(v.z);
    tb[(c4+3)*72 + k] = f2b(v.w);
  }
  __syncthreads();
  const int n = t >> 2, kq = (t & 3) * 16;
  ushort8v a = *(const ushort8v*)&tb[n*72 + kq];
  ushort8v b = *(const ushort8v*)&tb[n*72 + kq + 8];
  *(ushort8v*)(Wte + (size_t)(n0+n)*K + k0 + kq) = a;
  *(ushort8v*)(Wte + (size_t)(n0+n)*K + k0 + kq + 8) = b;
}

// ---------------- grouped GEMM, B^T bf16, 128x128 tile ----------------
// R1 measured-best structure (927.6 us total), occupancy-bumped: STAGES 3->2.
// LDS 49 KiB -> 33 KiB  =>  4 blocks/CU (was 3), 16 waves/CU. Mechanism: m114 —
// independent resident blocks co-schedule MFMA with other blocks' staging across
// the barrier drain; more blocks = more overlap. Depth-1 prefetch suffices:
// per-K-iter wall ~1.5 us >> HBM latency ~0.4 us.
//
// 2-stage software-pipelined K-loop: per iter wait vmcnt(4) = (STAGES-1)*4
// (group k, issued 2 iters back, must have landed; 4 newer loads in flight),
// raw s_barrier (no compiler vmcnt(0) drain), compute, raw s_barrier,
// issue group k+2 into the stage just freed. Exactly 4 vm-ops per iter so
// the manual vmcnt arithmetic stays exact.
//
// LDS swizzle (verified 0 conflicts in R1): rows are 64B (32 shorts = 4 x 16B
// chunks); 16B-read bank-group of cell [row][c] is 4*(row&1)+c. Read chunk
// c = (fq + (row>>1)) & 3 = (fq + (fr>>1)) & 3 walks all 8 groups across every
// 8 consecutive lanes (2 lanes/group = b128 hardware floor). Staging keeps
// linear LDS dests (global_load_lds requirement) and pre-rotates the per-lane
// GLOBAL k-chunk: thread t (row=t>>2, c_phys=t&3) loads chunk ((t&3)-(t>>3))&3.
// 4 lanes of a row cover one full 64B row segment (permuted) -> coalesced.
//
// EPI 0: Hout[seg+m][N] = bf16(relu(acc + bias))     (h = GEMM1 output)
// EPI 1: atomicAdd(Out[tok[m]][n], (acc + bias) * gate[m])
template<int EPI, int NX>
__global__ __launch_bounds__(256, 4)
void gemm_bt(const unsigned short* __restrict__ A, const unsigned short* __restrict__ Bt,
             const int K, const int N,
             const int* __restrict__ counts, const int* __restrict__ offs,
             const int* __restrict__ tab,
             const float* __restrict__ bias,
             unsigned short* __restrict__ Hout,
             float* __restrict__ Out,
             const int* __restrict__ slot_tok, const float* __restrict__ slot_gate) {
  constexpr int G = NX / 8;                 // n-panels per XCD
  const int bid = blockIdx.x;
  const int c = bid & 7;                    // XCD slot (dispatch is round-robin)
  const int s = bid >> 3;
  const int xi = c * G + (s % G);           // n-tile
  const int mt = s / G;                     // m-tile

  const int e = tab[mt*2];
  if (e < 0) return;
  const int m0  = tab[mt*2+1];
  const int cnt = counts[e];
  const int seg = offs[e];
  const int n0  = xi * TILE;

  // stage layout: [stage][ As 8KB | Bs 8KB ]  (2 stages = 32 KiB)
  __shared__ __align__(16) short smem[STAGES * 2 * TILE * BK];
  __shared__ int   s_tok[TILE];
  __shared__ float s_g[TILE];

  const int t = threadIdx.x;
  const int lane = t & 63;
  const int wv = t >> 6;
  const int wm = wv & 1, wn = wv >> 1;
  const int fr = lane & 15, fq = lane >> 4;

  if (EPI == 1 && t < TILE) {
    int rl = m0 + t;
    if (rl < cnt) { s_tok[t] = slot_tok[seg + rl]; s_g[t] = slot_gate[seg + rl]; }
    else          { s_tok[t] = 0;                  s_g[t] = 0.f; }
  }
  __syncthreads();   // real barrier (with drain) BEFORE prologue issues

  const unsigned short* Ae = A + (size_t)seg * K;
  const unsigned short* Be = Bt + (size_t)e * N * K + (size_t)n0 * K;

  // staging map: chunk index = t -> row = t>>2, LDS kc = t&3,
  // global kc = ((t&3) - (t>>3)) & 3   (inverse of the read rotation;
  // row+64 gives the same rotation mod 4, so both issues share kcg)
  const int row0 = t >> 2;
  const int kcg  = (((t & 3) - (t >> 3)) & 3) * 8;   // rotated global k-chunk (shorts)
  int ar0 = m0 + row0;        ar0 = ar0 < cnt ? ar0 : cnt - 1;
  int ar1 = m0 + row0 + 64;   ar1 = ar1 < cnt ? ar1 : cnt - 1;
  const unsigned short* rA0 = Ae + (size_t)ar0 * K + kcg;
  const unsigned short* rA1 = Ae + (size_t)ar1 * K + kcg;
  const unsigned short* rB0 = Be + (size_t)row0 * K + kcg;
  const unsigned short* rB1 = Be + (size_t)(row0 + 64) * K + kcg;
  const int ldsOff = wv * 1024;              // this wave's chunk within A (or B) half

  auto issue = [&](int koff, int soff) {
    char* pA = (char*)smem + soff + ldsOff;
    char* pB = (char*)smem + soff + 8192 + ldsOff;
    async16(rA0 + koff, pA);
    async16(rA1 + koff, pA + 4096);
    async16(rB0 + koff, pB);
    async16(rB1 + koff, pB + 4096);
  };

  f32x4 acc[4][4];
#pragma unroll
  for (int i = 0; i < 4; ++i)
#pragma unroll
    for (int j = 0; j < 4; ++j) acc[i][j] = (f32x4){0.f, 0.f, 0.f, 0.f};

  // prologue: fill the 2 stages (K >= STAGES*BK always here)
  issue(0 * BK, 0 * 16384);
  issue(1 * BK, 1 * 16384);

  // read-side rotated chunk: c = (fq + (row>>1)) & 3; row = {wm,wn}*64+i*16+fr
  // -> (row>>1)&3 = (fr>>1)&3 (other terms are multiples of 4), lane-constant.
  const int csw = ((fq + (fr >> 1)) & 3) * 8;

  int soff = 0;
  for (int k0 = 0; k0 < K; k0 += BK) {
    asm volatile("s_waitcnt vmcnt(4)" ::: "memory");   // group k landed; k+1 in flight
    asm volatile("s_barrier" ::: "memory");

    const short* As = (const short*)((const char*)smem + soff);
    const short* Bs = (const short*)((const char*)smem + soff + 8192);
    short8 af[4], bf[4];
#pragma unroll
    for (int i = 0; i < 4; ++i) {
      int row = wm*64 + i*16 + fr;
      af[i] = *(const short8*)&As[row*BK + csw];
    }
#pragma unroll
    for (int j = 0; j < 4; ++j) {
      int row = wn*64 + j*16 + fr;
      bf[j] = *(const short8*)&Bs[row*BK + csw];
    }
#pragma unroll
    for (int i = 0; i < 4; ++i)
#pragma unroll
      for (int j = 0; j < 4; ++j)
        acc[i][j] = __builtin_amdgcn_mfma_f32_16x16x32_bf16(af[i], bf[j], acc[i][j], 0, 0, 0);

    asm volatile("s_barrier" ::: "memory");            // all waves done reading this stage

    int kpre = k0 + STAGES * BK;                       // prefetch 2 ahead (clamped tail refetch
    if (kpre > K - BK) kpre = K - BK;                  //  keeps vmcnt accounting uniform)
    issue(kpre, soff);                                 // reuse the stage just freed
    soff += 16384; if (soff == STAGES * 16384) soff = 0;
  }

  if (EPI == 0) {
    const float* be = bias + (size_t)e * N;
#pragma unroll
    for (int j = 0; j < 4; ++j) {
      int col = n0 + wn*64 + j*16 + fr;
      float bv = be[col];
#pragma unroll
      for (int i = 0; i < 4; ++i) {
        int rb = m0 + wm*64 + i*16 + fq*4;   // expert-local row
#pragma unroll
        for (int r = 0; r < 4; ++r) {
          int rl = rb + r;
          if (rl < cnt) {
            float v = acc[i][j][r] + bv;
            v = v > 0.f ? v : 0.f;
            Hout[(size_t)(seg + rl) * N + col] = f2b(v);
          }
        }
      }
    }
  } else {
    const float* be = bias + (size_t)e * N;
#pragma unroll
    for (int j = 0; j < 4; ++j) {
      int col = n0 + wn*64 + j*16 + fr;
      float bv = be[col];
#pragma unroll
      for (int i = 0; i < 4; ++i) {
        int rbt = wm*64 + i*16 + fq*4;        // tile-local row
#pragma unroll
        for (int r = 0; r < 4; ++r) {
          int rlt = rbt + r;
          if (m0 + rlt < cnt) {
            float v = (acc[i][j][r] + bv) * s_g[rlt];
            unsafeAtomicAdd(Out + (size_t)s_tok[rlt] * N + col, v);
          }
        }
      }
    }
  }
}

extern "C" void kernel_launch(void* const* d_in, const int* in_sizes, int n_in,
                              void* d_out, int out_size, void* d_ws, size_t ws_size,
                              hipStream_t stream) {
  const float* x      = (const float*)d_in[0];
  const float* logits = (const float*)d_in[1];
  const float* noise  = (const float*)d_in[2];
  const float* W1     = (const float*)d_in[3];
  const float* b1     = (const float*)d_in[4];
  const float* W2     = (const float*)d_in[5];
  const float* b2     = (const float*)d_in[6];
  float* out = (float*)d_out;

  char* ws = (char*)d_ws;
  size_t off = 0;
  auto alloc = [&](size_t b) { size_t o = off; off = (off + b + 255) & ~(size_t)255; return o; };
  size_t o_counts = alloc(E_NUM * 4);
  size_t o_offs   = alloc((E_NUM + 1) * 4);
  size_t o_tab    = alloc((size_t)MAXTILES * 2 * 4);
  size_t o_ti     = alloc((size_t)T_TOK * 4 * 4);
  size_t o_tg     = alloc((size_t)T_TOK * 2 * 4);
  size_t o_stok   = alloc((size_t)2 * T_TOK * 4);
  size_t o_sg     = alloc((size_t)2 * T_TOK * 4);
  size_t o_xg     = alloc((size_t)2 * T_TOK * D_DIM * 2);
  size_t o_w1t    = alloc((size_t)E_NUM * D_DIM * H_DIM * 2);
  size_t o_w2t    = alloc((size_t)E_NUM * D_DIM * H_DIM * 2);
  size_t o_h      = alloc((size_t)2 * T_TOK * H_DIM * 2);
  if (off > ws_size) return;   // ws tier too small — will show as clean validation failure

  int*            counts = (int*)(ws + o_counts);
  int*            offsp  = (int*)(ws + o_offs);
  int*            tab    = (int*)(ws + o_tab);
  int*            ti     = (int*)(ws + o_ti);
  float*          tg     = (float*)(ws + o_tg);
  int*            stok   = (int*)(ws + o_stok);
  float*          sg     = (float*)(ws + o_sg);
  unsigned short* xg     = (unsigned short*)(ws + o_xg);
  unsigned short* w1t    = (unsigned short*)(ws + o_w1t);
  unsigned short* w2t    = (unsigned short*)(ws + o_w2t);
  unsigned short* h      = (unsigned short*)(ws + o_h);

  hipMemsetAsync(out, 0, (size_t)out_size * sizeof(float), stream);
  hipMemsetAsync(counts, 0, E_NUM * sizeof(int), stream);

  router_kernel<<<T_TOK / 256, 256, 0, stream>>>(logits, noise, counts, ti, tg);
  setup_kernel<<<1, 1, 0, stream>>>(counts, offsp, tab);
  gather_kernel<<<T_TOK, 256, 0, stream>>>(x, ti, tg, offsp, xg, stok, sg);

  transpose_kernel<<<dim3(H_DIM/64, D_DIM/64, E_NUM), 256, 0, stream>>>(W1, w1t, D_DIM, H_DIM);
  transpose_kernel<<<dim3(D_DIM/64, H_DIM/64, E_NUM), 256, 0, stream>>>(W2, w2t, H_DIM, D_DIM);

  gemm_bt<0, H_DIM/TILE><<<dim3((H_DIM/TILE) * MAXTILES), 256, 0, stream>>>(
      xg, w1t, D_DIM, H_DIM, counts, offsp, tab, b1, h, nullptr, nullptr, nullptr);
  gemm_bt<1, D_DIM/TILE><<<dim3((D_DIM/TILE) * MAXTILES), 256, 0, stream>>>(
      h, w2t, H_DIM, D_DIM, counts, offsp, tab, b2, nullptr, out, stok, sg);
}